// Round 16
// baseline (322.797 us; speedup 1.0000x reference)
//
#include <hip/hip_runtime.h>
#include <stdint.h>

typedef unsigned short u16;
typedef __attribute__((ext_vector_type(8))) short bf16x8;
typedef __attribute__((ext_vector_type(4))) float f32x4;

#define T_TOK 4096
#define D_DIM 1024
#define F_DIM 2048
#define NEXP 8
#define BM 128
#define BK 64
#define NDESC 112

struct Desc { int row_start; int nrows; int e; int pad; };

__device__ __forceinline__ u16 f2bf(float x) {
  union { float f; unsigned u; } v; v.f = x;
  unsigned r = v.u + 0x7FFFu + ((v.u >> 16) & 1u);
  return (u16)(r >> 16);
}
__device__ __forceinline__ float bf2f(u16 b) {
  union { unsigned u; float f; } v; v.u = ((unsigned)b) << 16;
  return v.f;
}

#define GLD16(g, l) __builtin_amdgcn_global_load_lds( \
    (const __attribute__((address_space(1))) unsigned int*)(const void*)(g), \
    (__attribute__((address_space(3))) unsigned int*)(void*)(l), 16, 0, 0)

// ======== prep: weight convert+transpose (z<27) + router/X-convert (z>=27) ========
__global__ void k_prep(const float* __restrict__ X, const float* __restrict__ Wr,
                       const float* __restrict__ Wg_s, const float* __restrict__ Wu_s,
                       const float* __restrict__ Wd_s, const float* __restrict__ Wg,
                       const float* __restrict__ Wu, const float* __restrict__ Wd,
                       u16* __restrict__ Xb, u16* __restrict__ WgTs, u16* __restrict__ WuTs,
                       u16* __restrict__ WdTs, u16* __restrict__ WgT, u16* __restrict__ WuT,
                       u16* __restrict__ WdT, int* __restrict__ tk_idx,
                       float* __restrict__ tk_w) {
  const int z = blockIdx.z;
  const int tid = threadIdx.x;
  if (z >= 27) {
    // ---- router: fp32 logits, softmax, top-2, re-softmax; + X->bf16 ----
    const int w = tid >> 6, lane = tid & 63;
    const int t = (((z - 27) * 512) + blockIdx.x * 32 + blockIdx.y) * 4 + w;
    float acc[8] = {0.f, 0.f, 0.f, 0.f, 0.f, 0.f, 0.f, 0.f};
    const float* xr = X + (size_t)t * D_DIM;
    u16* xb = Xb + (size_t)t * D_DIM;
    #pragma unroll
    for (int it = 0; it < 4; it++) {
      const int i0 = it * 256 + lane * 4;
      float4 xv = *(const float4*)(xr + i0);
      union { u16 a[4]; uint2 v; } ob;
      ob.a[0] = f2bf(xv.x); ob.a[1] = f2bf(xv.y); ob.a[2] = f2bf(xv.z); ob.a[3] = f2bf(xv.w);
      *(uint2*)(xb + i0) = ob.v;
      float xs[4] = {xv.x, xv.y, xv.z, xv.w};
      #pragma unroll
      for (int j = 0; j < 4; j++) {
        const float4* wrp = (const float4*)(Wr + (size_t)(i0 + j) * 8);
        float4 w0 = wrp[0], w1 = wrp[1];
        float x = xs[j];
        acc[0] += x * w0.x; acc[1] += x * w0.y; acc[2] += x * w0.z; acc[3] += x * w0.w;
        acc[4] += x * w1.x; acc[5] += x * w1.y; acc[6] += x * w1.z; acc[7] += x * w1.w;
      }
    }
    #pragma unroll
    for (int m = 32; m; m >>= 1) {
      #pragma unroll
      for (int e = 0; e < 8; e++) acc[e] += __shfl_xor(acc[e], m);
    }
    float mx = acc[0];
    #pragma unroll
    for (int e = 1; e < 8; e++) mx = fmaxf(mx, acc[e]);
    float p[8], Z = 0.f;
    #pragma unroll
    for (int e = 0; e < 8; e++) { p[e] = expf(acc[e] - mx); Z += p[e]; }
    float inv = 1.f / Z;
    #pragma unroll
    for (int e = 0; e < 8; e++) p[e] *= inv;
    int e1 = 0; float p1 = p[0];
    #pragma unroll
    for (int e = 1; e < 8; e++) if (p[e] > p1) { p1 = p[e]; e1 = e; }
    int e2 = -1; float p2 = -1.f;
    #pragma unroll
    for (int e = 0; e < 8; e++) if (e != e1 && p[e] > p2) { p2 = p[e]; e2 = e; }
    float bb = expf(p2 - p1);
    float w1v = 1.f / (1.f + bb), w2v = 1.f - w1v;
    if (lane == 0) {
      tk_idx[t * 2] = e1; tk_idx[t * 2 + 1] = e2;
      tk_w[t * 2] = w1v;  tk_w[t * 2 + 1] = w2v;
    }
    return;
  }
  // ---- tconv slice ----
  const float* src; u16* dst; int R, C;
  const size_t sz = (size_t)D_DIM * F_DIM;
  if (z < 8)       { src = Wg + sz * z;        dst = WgT + sz * z;        R = D_DIM; C = F_DIM; }
  else if (z < 16) { src = Wu + sz * (z - 8);  dst = WuT + sz * (z - 8);  R = D_DIM; C = F_DIM; }
  else if (z < 24) { src = Wd + sz * (z - 16); dst = WdT + sz * (z - 16); R = F_DIM; C = D_DIM; }
  else if (z == 24){ src = Wg_s; dst = WgTs; R = D_DIM; C = F_DIM; }
  else if (z == 25){ src = Wu_s; dst = WuTs; R = D_DIM; C = F_DIM; }
  else             { src = Wd_s; dst = WdTs; R = F_DIM; C = D_DIM; }
  const bool tall = (R > C);
  const int rb = (tall ? blockIdx.y : blockIdx.x) * 64;
  const int cb = (tall ? blockIdx.x : blockIdx.y) * 64;
  __shared__ u16 tile[64][72];
  const int lr = tid >> 4, lc = (tid & 15) * 4;
  #pragma unroll
  for (int p = 0; p < 4; p++) {
    int r = p * 16 + lr;
    float4 v = *(const float4*)(src + (size_t)(rb + r) * C + cb + lc);
    tile[r][lc + 0] = f2bf(v.x); tile[r][lc + 1] = f2bf(v.y);
    tile[r][lc + 2] = f2bf(v.z); tile[r][lc + 3] = f2bf(v.w);
  }
  __syncthreads();
  #pragma unroll
  for (int it = 0; it < 2; it++) {
    int chunk = it * 256 + tid;
    int c = chunk >> 3, r0 = (chunk & 7) * 8;
    u16 o[8];
    #pragma unroll
    for (int i = 0; i < 8; i++) o[i] = tile[r0 + i][c];
    *(uint4*)(dst + (size_t)(cb + c) * R + rb + r0) = *(const uint4*)o;
  }
}

// ======== scan_scatter: histogram + prefix + descs + scatter, one 1024-thr block ========
__global__ void k_scan_scatter(const int* __restrict__ tk_idx, Desc* __restrict__ descs,
                               int* __restrict__ tok, int* __restrict__ pos) {
  __shared__ int cnt[8], curs[8];
  const int tid = threadIdx.x;
  if (tid < 8) cnt[tid] = 0;
  __syncthreads();
  for (int i = tid; i < 2 * T_TOK; i += 1024) atomicAdd(&cnt[tk_idx[i]], 1);
  __syncthreads();
  if (tid < 64) {
    int c[8], off[9], tst[9];
    off[0] = 0; tst[0] = 0;
    #pragma unroll
    for (int e = 0; e < 8; e++) {
      c[e] = cnt[e];
      off[e + 1] = off[e] + c[e];
      tst[e + 1] = tst[e] + ((c[e] + 127) >> 7);
    }
    if (tid < 8) curs[tid] = off[tid];
    const int tr = tst[8];
    for (int i = tid; i < NDESC; i += 64) {
      Desc dd; dd.nrows = 0; dd.row_start = 0; dd.e = 0; dd.pad = 0;
      if (i < tr) {
        int e = 0;
        #pragma unroll
        for (int q = 0; q < 7; q++) if (i >= tst[q + 1]) e = q + 1;
        int s = (i - tst[e]) << 7;
        dd.row_start = off[e] + s;
        int rem = c[e] - s;
        dd.nrows = rem < 128 ? rem : 128;
        dd.e = e;
      } else if (i < tr + T_TOK / 128) {
        int j = i - tr;
        dd.row_start = 2 * T_TOK + j * 128; dd.nrows = 128; dd.e = NEXP;
      }
      descs[i] = dd;
    }
  }
  __syncthreads();
  for (int t = tid; t < T_TOK; t += 1024) {
    #pragma unroll
    for (int k = 0; k < 2; k++) {
      int e = tk_idx[t * 2 + k];
      int p = atomicAdd(&curs[e], 1);
      tok[p] = t;
      pos[t * 2 + k] = p;
    }
    tok[2 * T_TOK + t] = t;
  }
}

// ======== GEMM1 fused, low-register (R9/R13/R15-proven, 135us): h = silu(X@Wg^T)*(X@Wu^T) ========
// BM=128, BN=64(g)+64(u); 4 waves 2Mx2N; acc 64 AGPR -> 3 waves/SIMD; LDS 32KB. Frozen.
__global__ __launch_bounds__(256, 3) void k_gemm1(
    const u16* __restrict__ Xb, const u16* __restrict__ WgT, const u16* __restrict__ WuT,
    const u16* __restrict__ WgTs, const u16* __restrict__ WuTs,
    const int* __restrict__ tok, const Desc* __restrict__ descs, u16* __restrict__ h) {
  __shared__ u16 As[128 * BK];
  __shared__ u16 Bgs[64 * BK];
  __shared__ u16 Bus[64 * BK];
  const Desc d = descs[blockIdx.y];
  if (d.nrows <= 0) return;
  const int n0 = (int)blockIdx.x * 64;
  const u16* BTg = (d.e == NEXP) ? WgTs : (WgT + (size_t)d.e * F_DIM * D_DIM);
  const u16* BTu = (d.e == NEXP) ? WuTs : (WuT + (size_t)d.e * F_DIM * D_DIM);
  const int tid = threadIdx.x;
  const int w = tid >> 6, lane = tid & 63;

  const int srow = tid >> 3;
  const int scol = ((tid & 7) ^ (srow & 7)) * 8;
  const u16* pA[4]; const u16* pBg[2]; const u16* pBu[2];
  #pragma unroll
  for (int j = 0; j < 4; j++)
    pA[j] = Xb + (size_t)tok[d.row_start + j * 32 + srow] * D_DIM + scol;
  #pragma unroll
  for (int j = 0; j < 2; j++) {
    pBg[j] = BTg + (size_t)(n0 + j * 32 + srow) * D_DIM + scol;
    pBu[j] = BTu + (size_t)(n0 + j * 32 + srow) * D_DIM + scol;
  }
  const unsigned sdst = (unsigned)tid * 16;

  f32x4 ag[4][2], au[4][2];
  #pragma unroll
  for (int m = 0; m < 4; m++)
    #pragma unroll
    for (int n = 0; n < 2; n++) { ag[m][n] = (f32x4)0.f; au[m][n] = (f32x4)0.f; }

  const int wr = w >> 1, wc = w & 1;
  const int sw = lane & 7;
  const u16* aP = As  + (wr * 64 + (lane & 15)) * BK;
  const u16* gP = Bgs + (wc * 32 + (lane & 15)) * BK;
  const u16* uP = Bus + (wc * 32 + (lane & 15)) * BK;
  const int slot0 = ((lane >> 4) ^ sw) * 8;
  const int slot1 = (((lane >> 4) + 4) ^ sw) * 8;

  for (int k0 = 0; k0 < D_DIM; k0 += BK) {
    #pragma unroll
    for (int j = 0; j < 4; j++) GLD16(pA[j] + k0,  (char*)As  + j * 4096 + sdst);
    #pragma unroll
    for (int j = 0; j < 2; j++) GLD16(pBg[j] + k0, (char*)Bgs + j * 4096 + sdst);
    #pragma unroll
    for (int j = 0; j < 2; j++) GLD16(pBu[j] + k0, (char*)Bus + j * 4096 + sdst);
    __syncthreads();
    #pragma unroll
    for (int ks = 0; ks < 2; ks++) {
      const int sl = ks ? slot1 : slot0;
      bf16x8 af[4], bg[2], bu[2];
      #pragma unroll
      for (int m = 0; m < 4; m++) af[m] = *(const bf16x8*)(aP + m * 16 * BK + sl);
      #pragma unroll
      for (int n = 0; n < 2; n++) { bg[n] = *(const bf16x8*)(gP + n * 16 * BK + sl);
                                    bu[n] = *(const bf16x8*)(uP + n * 16 * BK + sl); }
      #pragma unroll
      for (int m = 0; m < 4; m++)
        #pragma unroll
        for (int n = 0; n < 2; n++) {
          ag[m][n] = __builtin_amdgcn_mfma_f32_16x16x32_bf16(af[m], bg[n], ag[m][n], 0, 0, 0);
          au[m][n] = __builtin_amdgcn_mfma_f32_16x16x32_bf16(af[m], bu[n], au[m][n], 0, 0, 0);
        }
    }
    __syncthreads();
  }

  #pragma unroll
  for (int m = 0; m < 4; m++) {
    const int rbase = wr * 64 + m * 16 + ((lane >> 4) << 2);
    #pragma unroll
    for (int n = 0; n < 2; n++) {
      const int col = n0 + wc * 32 + n * 16 + (lane & 15);
      #pragma unroll
      for (int j = 0; j < 4; j++) {
        const int r = rbase + j;
        if (r < d.nrows) {
          float gf = ag[m][n][j], uf = au[m][n][j];
          float hv = gf / (1.f + expf(-gf)) * uf;
          h[(size_t)(d.row_start + r) * F_DIM + col] = f2bf(hv);
        }
      }
    }
  }
}

// ======== GEMM2, 8-wave low-register: eout(bf16)/out(f32) = H @ Wd ========
// Same 128x256 block tile as R7/R15 (B-traffic unchanged — not the R10 mistake),
// but 512 thr = 8 waves (2M x 4N): per-wave 64x64, acc[4][4] = 64 AGPR (was 128),
// staging pointers 12 -> 6. Est ~55-64 arch VGPR -> under launch_bounds(512,4)'s
// 128-reg unified cap -> 4 waves/SIMD (was 2). Per-wave MFMA cluster stays 32
// (unlike R14's 8 — ILP preserved). LDS 48KB. T2 swizzle unchanged.
__global__ __launch_bounds__(512, 4) void k_gemm2(
    const u16* __restrict__ h, const u16* __restrict__ WdT, const u16* __restrict__ WdTs,
    const Desc* __restrict__ descs, u16* __restrict__ eout, float* __restrict__ out) {
  __shared__ u16 As[BM * BK];          // 16 KB
  __shared__ u16 Bs[256 * BK];         // 32 KB
  const Desc d = descs[blockIdx.y];
  if (d.nrows <= 0) return;
  const int n0 = (int)blockIdx.x * 256;
  const u16* BT = (d.e == NEXP) ? WdTs : (WdT + (size_t)d.e * D_DIM * F_DIM);
  const int tid = threadIdx.x;
  const int w = tid >> 6, lane = tid & 63;

  // staging: each GLD16 sweep = 512thr*16B = 8KB = 64 rows of 128B
  const int srow = tid >> 3;                        // 0..63
  const int scol = ((tid & 7) ^ (srow & 7)) * 8;
  const u16* pA[2]; const u16* pB[4];
  #pragma unroll
  for (int j = 0; j < 2; j++)
    pA[j] = h + (size_t)(d.row_start + j * 64 + srow) * F_DIM + scol;
  #pragma unroll
  for (int j = 0; j < 4; j++)
    pB[j] = BT + (size_t)(n0 + j * 64 + srow) * F_DIM + scol;
  const unsigned sdst = (unsigned)tid * 16;

  f32x4 acc[4][4];
  #pragma unroll
  for (int m = 0; m < 4; m++)
    #pragma unroll
    for (int n = 0; n < 4; n++) acc[m][n] = (f32x4)0.f;

  const int wr = w >> 2, wc = w & 3;               // wr 0..1 (64-row half), wc 0..3 (64-col quarter)
  const int sw = lane & 7;
  const u16* aP = As + (wr * 64 + (lane & 15)) * BK;
  const u16* bP = Bs + (wc * 64 + (lane & 15)) * BK;
  const int slot0 = ((lane >> 4) ^ sw) * 8;
  const int slot1 = (((lane >> 4) + 4) ^ sw) * 8;

  for (int k0 = 0; k0 < F_DIM; k0 += BK) {
    #pragma unroll
    for (int j = 0; j < 2; j++) GLD16(pA[j] + k0, (char*)As + j * 8192 + sdst);
    #pragma unroll
    for (int j = 0; j < 4; j++) GLD16(pB[j] + k0, (char*)Bs + j * 8192 + sdst);
    __syncthreads();
    #pragma unroll
    for (int ks = 0; ks < 2; ks++) {
      const int sl = ks ? slot1 : slot0;
      bf16x8 af[4], bf[4];
      #pragma unroll
      for (int m = 0; m < 4; m++) af[m] = *(const bf16x8*)(aP + m * 16 * BK + sl);
      #pragma unroll
      for (int n = 0; n < 4; n++) bf[n] = *(const bf16x8*)(bP + n * 16 * BK + sl);
      #pragma unroll
      for (int m = 0; m < 4; m++)
        #pragma unroll
        for (int n = 0; n < 4; n++)
          acc[m][n] = __builtin_amdgcn_mfma_f32_16x16x32_bf16(af[m], bf[n], acc[m][n], 0, 0, 0);
    }
    __syncthreads();
  }

  #pragma unroll
  for (int m = 0; m < 4; m++) {
    const int rbase = wr * 64 + m * 16 + ((lane >> 4) << 2);
    #pragma unroll
    for (int n = 0; n < 4; n++) {
      const int col2 = n0 + wc * 64 + n * 16 + (lane & 15);
      #pragma unroll
      for (int j = 0; j < 4; j++) {
        const int r = rbase + j;
        if (r < d.nrows) {
          const int grow = d.row_start + r;
          float v = acc[m][n][j];
          if (d.e == NEXP) out[(size_t)(grow - 2 * T_TOK) * D_DIM + col2] = v;
          else             eout[(size_t)grow * D_DIM + col2] = f2bf(v);
        }
      }
    }
  }
}

// ------- combine (uint4-vectorized, 1024 blocks x 4 rows): out[t] += w0*e[p0]+w1*e[p1] -------
__global__ void k_combine(const u16* __restrict__ eout, const int* __restrict__ pos,
                          const float* __restrict__ tk_w, float* __restrict__ out) {
  const int t = blockIdx.x * 4 + (threadIdx.x >> 6);
  const int dc = (threadIdx.x & 63) * 8;
  const int p0 = pos[t * 2], p1 = pos[t * 2 + 1];
  const float w0 = tk_w[t * 2], w1 = tk_w[t * 2 + 1];
  #pragma unroll
  for (int hh = 0; hh < 2; hh++) {
    const int c = dc + hh * 512;
    float* op = out + (size_t)t * D_DIM + c;
    union { uint4 v; u16 a[8]; } av, bv;
    av.v = *(const uint4*)(eout + (size_t)p0 * D_DIM + c);
    bv.v = *(const uint4*)(eout + (size_t)p1 * D_DIM + c);
    float4 o0 = *(float4*)op;
    float4 o1 = *(float4*)(op + 4);
    o0.x += w0 * bf2f(av.a[0]) + w1 * bf2f(bv.a[0]);
    o0.y += w0 * bf2f(av.a[1]) + w1 * bf2f(bv.a[1]);
    o0.z += w0 * bf2f(av.a[2]) + w1 * bf2f(bv.a[2]);
    o0.w += w0 * bf2f(av.a[3]) + w1 * bf2f(bv.a[3]);
    o1.x += w0 * bf2f(av.a[4]) + w1 * bf2f(bv.a[4]);
    o1.y += w0 * bf2f(av.a[5]) + w1 * bf2f(bv.a[5]);
    o1.z += w0 * bf2f(av.a[6]) + w1 * bf2f(bv.a[6]);
    o1.w += w0 * bf2f(av.a[7]) + w1 * bf2f(bv.a[7]);
    *(float4*)op = o0;
    *(float4*)(op + 4) = o1;
  }
}

extern "C" void kernel_launch(void* const* d_in, const int* in_sizes, int n_in,
                              void* d_out, int out_size, void* d_ws, size_t ws_size,
                              hipStream_t stream) {
  const float* X    = (const float*)d_in[0];
  const float* Wr   = (const float*)d_in[1];
  const float* Wg_s = (const float*)d_in[2];
  const float* Wu_s = (const float*)d_in[3];
  const float* Wd_s = (const float*)d_in[4];
  const float* Wg   = (const float*)d_in[5];
  const float* Wu   = (const float*)d_in[6];
  const float* Wd   = (const float*)d_in[7];
  float* out = (float*)d_out;

  char* ws = (char*)d_ws;
  size_t o = 0;
  auto alloc = [&](size_t bytes) -> void* {
    void* p = ws + o;
    o += (bytes + 255) & ~(size_t)255;
    return p;
  };
  u16* Xb    = (u16*)alloc((size_t)T_TOK * D_DIM * 2);
  u16* WgTs  = (u16*)alloc((size_t)F_DIM * D_DIM * 2);
  u16* WuTs  = (u16*)alloc((size_t)F_DIM * D_DIM * 2);
  u16* WdTs  = (u16*)alloc((size_t)D_DIM * F_DIM * 2);
  u16* WgT   = (u16*)alloc((size_t)NEXP * F_DIM * D_DIM * 2);
  u16* WuT   = (u16*)alloc((size_t)NEXP * F_DIM * D_DIM * 2);
  u16* WdT   = (u16*)alloc((size_t)NEXP * D_DIM * F_DIM * 2);
  u16* h     = (u16*)alloc((size_t)(3 * T_TOK) * F_DIM * 2);
  u16* eout  = (u16*)alloc((size_t)(2 * T_TOK) * D_DIM * 2);
  int* tk_idx= (int*)alloc((size_t)T_TOK * 2 * 4);
  float* tk_w= (float*)alloc((size_t)T_TOK * 2 * 4);
  int* pos   = (int*)alloc((size_t)T_TOK * 2 * 4);
  int* tok   = (int*)alloc((size_t)(3 * T_TOK) * 4);
  Desc* descs= (Desc*)alloc(NDESC * sizeof(Desc));
  if (o > ws_size) return;

  k_prep<<<dim3(16, 32, 29), 256, 0, stream>>>(X, Wr, Wg_s, Wu_s, Wd_s, Wg, Wu, Wd,
                                               Xb, WgTs, WuTs, WdTs, WgT, WuT, WdT,
                                               tk_idx, tk_w);
  k_scan_scatter<<<1, 1024, 0, stream>>>(tk_idx, descs, tok, pos);
  k_gemm1<<<dim3(32, NDESC), 256, 0, stream>>>(Xb, WgT, WuT, WgTs, WuTs, tok, descs, h);
  k_gemm2<<<dim3(4, NDESC), 512, 0, stream>>>(h, WdT, WdTs, descs, eout, out);
  k_combine<<<T_TOK / 4, 256, 0, stream>>>(eout, pos, tk_w, out);
}

// Round 17
// 282.109 us; speedup vs baseline: 1.1442x; 1.1442x over previous
//
#include <hip/hip_runtime.h>
#include <stdint.h>

typedef unsigned short u16;
typedef __attribute__((ext_vector_type(8))) short bf16x8;
typedef __attribute__((ext_vector_type(4))) float f32x4;

#define T_TOK 4096
#define D_DIM 1024
#define F_DIM 2048
#define NEXP 8
#define BM 128
#define BK 64
#define NDESC 112

struct Desc { int row_start; int nrows; int e; int pad; };

__device__ __forceinline__ u16 f2bf(float x) {
  union { float f; unsigned u; } v; v.f = x;
  unsigned r = v.u + 0x7FFFu + ((v.u >> 16) & 1u);
  return (u16)(r >> 16);
}
__device__ __forceinline__ float bf2f(u16 b) {
  union { unsigned u; float f; } v; v.u = ((unsigned)b) << 16;
  return v.f;
}

#define GLD16(g, l) __builtin_amdgcn_global_load_lds( \
    (const __attribute__((address_space(1))) unsigned int*)(const void*)(g), \
    (__attribute__((address_space(3))) unsigned int*)(void*)(l), 16, 0, 0)

// ======== prep: weight convert+transpose (z<27) + router/X-convert (z>=27) ========
__global__ void k_prep(const float* __restrict__ X, const float* __restrict__ Wr,
                       const float* __restrict__ Wg_s, const float* __restrict__ Wu_s,
                       const float* __restrict__ Wd_s, const float* __restrict__ Wg,
                       const float* __restrict__ Wu, const float* __restrict__ Wd,
                       u16* __restrict__ Xb, u16* __restrict__ WgTs, u16* __restrict__ WuTs,
                       u16* __restrict__ WdTs, u16* __restrict__ WgT, u16* __restrict__ WuT,
                       u16* __restrict__ WdT, int* __restrict__ tk_idx,
                       float* __restrict__ tk_w) {
  const int z = blockIdx.z;
  const int tid = threadIdx.x;
  if (z >= 27) {
    // ---- router: fp32 logits, softmax, top-2, re-softmax; + X->bf16 ----
    const int w = tid >> 6, lane = tid & 63;
    const int t = (((z - 27) * 512) + blockIdx.x * 32 + blockIdx.y) * 4 + w;
    float acc[8] = {0.f, 0.f, 0.f, 0.f, 0.f, 0.f, 0.f, 0.f};
    const float* xr = X + (size_t)t * D_DIM;
    u16* xb = Xb + (size_t)t * D_DIM;
    #pragma unroll
    for (int it = 0; it < 4; it++) {
      const int i0 = it * 256 + lane * 4;
      float4 xv = *(const float4*)(xr + i0);
      union { u16 a[4]; uint2 v; } ob;
      ob.a[0] = f2bf(xv.x); ob.a[1] = f2bf(xv.y); ob.a[2] = f2bf(xv.z); ob.a[3] = f2bf(xv.w);
      *(uint2*)(xb + i0) = ob.v;
      float xs[4] = {xv.x, xv.y, xv.z, xv.w};
      #pragma unroll
      for (int j = 0; j < 4; j++) {
        const float4* wrp = (const float4*)(Wr + (size_t)(i0 + j) * 8);
        float4 w0 = wrp[0], w1 = wrp[1];
        float x = xs[j];
        acc[0] += x * w0.x; acc[1] += x * w0.y; acc[2] += x * w0.z; acc[3] += x * w0.w;
        acc[4] += x * w1.x; acc[5] += x * w1.y; acc[6] += x * w1.z; acc[7] += x * w1.w;
      }
    }
    #pragma unroll
    for (int m = 32; m; m >>= 1) {
      #pragma unroll
      for (int e = 0; e < 8; e++) acc[e] += __shfl_xor(acc[e], m);
    }
    float mx = acc[0];
    #pragma unroll
    for (int e = 1; e < 8; e++) mx = fmaxf(mx, acc[e]);
    float p[8], Z = 0.f;
    #pragma unroll
    for (int e = 0; e < 8; e++) { p[e] = expf(acc[e] - mx); Z += p[e]; }
    float inv = 1.f / Z;
    #pragma unroll
    for (int e = 0; e < 8; e++) p[e] *= inv;
    int e1 = 0; float p1 = p[0];
    #pragma unroll
    for (int e = 1; e < 8; e++) if (p[e] > p1) { p1 = p[e]; e1 = e; }
    int e2 = -1; float p2 = -1.f;
    #pragma unroll
    for (int e = 0; e < 8; e++) if (e != e1 && p[e] > p2) { p2 = p[e]; e2 = e; }
    float bb = expf(p2 - p1);
    float w1v = 1.f / (1.f + bb), w2v = 1.f - w1v;
    if (lane == 0) {
      tk_idx[t * 2] = e1; tk_idx[t * 2 + 1] = e2;
      tk_w[t * 2] = w1v;  tk_w[t * 2 + 1] = w2v;
    }
    return;
  }
  // ---- tconv slice ----
  const float* src; u16* dst; int R, C;
  const size_t sz = (size_t)D_DIM * F_DIM;
  if (z < 8)       { src = Wg + sz * z;        dst = WgT + sz * z;        R = D_DIM; C = F_DIM; }
  else if (z < 16) { src = Wu + sz * (z - 8);  dst = WuT + sz * (z - 8);  R = D_DIM; C = F_DIM; }
  else if (z < 24) { src = Wd + sz * (z - 16); dst = WdT + sz * (z - 16); R = F_DIM; C = D_DIM; }
  else if (z == 24){ src = Wg_s; dst = WgTs; R = D_DIM; C = F_DIM; }
  else if (z == 25){ src = Wu_s; dst = WuTs; R = D_DIM; C = F_DIM; }
  else             { src = Wd_s; dst = WdTs; R = F_DIM; C = D_DIM; }
  const bool tall = (R > C);
  const int rb = (tall ? blockIdx.y : blockIdx.x) * 64;
  const int cb = (tall ? blockIdx.x : blockIdx.y) * 64;
  __shared__ u16 tile[64][72];
  const int lr = tid >> 4, lc = (tid & 15) * 4;
  #pragma unroll
  for (int p = 0; p < 4; p++) {
    int r = p * 16 + lr;
    float4 v = *(const float4*)(src + (size_t)(rb + r) * C + cb + lc);
    tile[r][lc + 0] = f2bf(v.x); tile[r][lc + 1] = f2bf(v.y);
    tile[r][lc + 2] = f2bf(v.z); tile[r][lc + 3] = f2bf(v.w);
  }
  __syncthreads();
  #pragma unroll
  for (int it = 0; it < 2; it++) {
    int chunk = it * 256 + tid;
    int c = chunk >> 3, r0 = (chunk & 7) * 8;
    u16 o[8];
    #pragma unroll
    for (int i = 0; i < 8; i++) o[i] = tile[r0 + i][c];
    *(uint4*)(dst + (size_t)(cb + c) * R + rb + r0) = *(const uint4*)o;
  }
}

// ======== scan_scatter: histogram + prefix + descs + scatter, one 1024-thr block ========
__global__ void k_scan_scatter(const int* __restrict__ tk_idx, Desc* __restrict__ descs,
                               int* __restrict__ tok, int* __restrict__ pos) {
  __shared__ int cnt[8], curs[8];
  const int tid = threadIdx.x;
  if (tid < 8) cnt[tid] = 0;
  __syncthreads();
  for (int i = tid; i < 2 * T_TOK; i += 1024) atomicAdd(&cnt[tk_idx[i]], 1);
  __syncthreads();
  if (tid < 64) {
    int c[8], off[9], tst[9];
    off[0] = 0; tst[0] = 0;
    #pragma unroll
    for (int e = 0; e < 8; e++) {
      c[e] = cnt[e];
      off[e + 1] = off[e] + c[e];
      tst[e + 1] = tst[e] + ((c[e] + 127) >> 7);
    }
    if (tid < 8) curs[tid] = off[tid];
    const int tr = tst[8];
    for (int i = tid; i < NDESC; i += 64) {
      Desc dd; dd.nrows = 0; dd.row_start = 0; dd.e = 0; dd.pad = 0;
      if (i < tr) {
        int e = 0;
        #pragma unroll
        for (int q = 0; q < 7; q++) if (i >= tst[q + 1]) e = q + 1;
        int s = (i - tst[e]) << 7;
        dd.row_start = off[e] + s;
        int rem = c[e] - s;
        dd.nrows = rem < 128 ? rem : 128;
        dd.e = e;
      } else if (i < tr + T_TOK / 128) {
        int j = i - tr;
        dd.row_start = 2 * T_TOK + j * 128; dd.nrows = 128; dd.e = NEXP;
      }
      descs[i] = dd;
    }
  }
  __syncthreads();
  for (int t = tid; t < T_TOK; t += 1024) {
    #pragma unroll
    for (int k = 0; k < 2; k++) {
      int e = tk_idx[t * 2 + k];
      int p = atomicAdd(&curs[e], 1);
      tok[p] = t;
      pos[t * 2 + k] = p;
    }
    tok[2 * T_TOK + t] = t;
  }
}

// ======== GEMM1 fused, low-register (R9/R13/R15-proven, 135us): h = silu(X@Wg^T)*(X@Wu^T) ========
// BM=128, BN=64(g)+64(u); 4 waves 2Mx2N; acc 64 AGPR -> 3 waves/SIMD; LDS 32KB. Frozen.
__global__ __launch_bounds__(256, 3) void k_gemm1(
    const u16* __restrict__ Xb, const u16* __restrict__ WgT, const u16* __restrict__ WuT,
    const u16* __restrict__ WgTs, const u16* __restrict__ WuTs,
    const int* __restrict__ tok, const Desc* __restrict__ descs, u16* __restrict__ h) {
  __shared__ u16 As[128 * BK];
  __shared__ u16 Bgs[64 * BK];
  __shared__ u16 Bus[64 * BK];
  const Desc d = descs[blockIdx.y];
  if (d.nrows <= 0) return;
  const int n0 = (int)blockIdx.x * 64;
  const u16* BTg = (d.e == NEXP) ? WgTs : (WgT + (size_t)d.e * F_DIM * D_DIM);
  const u16* BTu = (d.e == NEXP) ? WuTs : (WuT + (size_t)d.e * F_DIM * D_DIM);
  const int tid = threadIdx.x;
  const int w = tid >> 6, lane = tid & 63;

  const int srow = tid >> 3;
  const int scol = ((tid & 7) ^ (srow & 7)) * 8;
  const u16* pA[4]; const u16* pBg[2]; const u16* pBu[2];
  #pragma unroll
  for (int j = 0; j < 4; j++)
    pA[j] = Xb + (size_t)tok[d.row_start + j * 32 + srow] * D_DIM + scol;
  #pragma unroll
  for (int j = 0; j < 2; j++) {
    pBg[j] = BTg + (size_t)(n0 + j * 32 + srow) * D_DIM + scol;
    pBu[j] = BTu + (size_t)(n0 + j * 32 + srow) * D_DIM + scol;
  }
  const unsigned sdst = (unsigned)tid * 16;

  f32x4 ag[4][2], au[4][2];
  #pragma unroll
  for (int m = 0; m < 4; m++)
    #pragma unroll
    for (int n = 0; n < 2; n++) { ag[m][n] = (f32x4)0.f; au[m][n] = (f32x4)0.f; }

  const int wr = w >> 1, wc = w & 1;
  const int sw = lane & 7;
  const u16* aP = As  + (wr * 64 + (lane & 15)) * BK;
  const u16* gP = Bgs + (wc * 32 + (lane & 15)) * BK;
  const u16* uP = Bus + (wc * 32 + (lane & 15)) * BK;
  const int slot0 = ((lane >> 4) ^ sw) * 8;
  const int slot1 = (((lane >> 4) + 4) ^ sw) * 8;

  for (int k0 = 0; k0 < D_DIM; k0 += BK) {
    #pragma unroll
    for (int j = 0; j < 4; j++) GLD16(pA[j] + k0,  (char*)As  + j * 4096 + sdst);
    #pragma unroll
    for (int j = 0; j < 2; j++) GLD16(pBg[j] + k0, (char*)Bgs + j * 4096 + sdst);
    #pragma unroll
    for (int j = 0; j < 2; j++) GLD16(pBu[j] + k0, (char*)Bus + j * 4096 + sdst);
    __syncthreads();
    #pragma unroll
    for (int ks = 0; ks < 2; ks++) {
      const int sl = ks ? slot1 : slot0;
      bf16x8 af[4], bg[2], bu[2];
      #pragma unroll
      for (int m = 0; m < 4; m++) af[m] = *(const bf16x8*)(aP + m * 16 * BK + sl);
      #pragma unroll
      for (int n = 0; n < 2; n++) { bg[n] = *(const bf16x8*)(gP + n * 16 * BK + sl);
                                    bu[n] = *(const bf16x8*)(uP + n * 16 * BK + sl); }
      #pragma unroll
      for (int m = 0; m < 4; m++)
        #pragma unroll
        for (int n = 0; n < 2; n++) {
          ag[m][n] = __builtin_amdgcn_mfma_f32_16x16x32_bf16(af[m], bg[n], ag[m][n], 0, 0, 0);
          au[m][n] = __builtin_amdgcn_mfma_f32_16x16x32_bf16(af[m], bu[n], au[m][n], 0, 0, 0);
        }
    }
    __syncthreads();
  }

  #pragma unroll
  for (int m = 0; m < 4; m++) {
    const int rbase = wr * 64 + m * 16 + ((lane >> 4) << 2);
    #pragma unroll
    for (int n = 0; n < 2; n++) {
      const int col = n0 + wc * 32 + n * 16 + (lane & 15);
      #pragma unroll
      for (int j = 0; j < 4; j++) {
        const int r = rbase + j;
        if (r < d.nrows) {
          float gf = ag[m][n][j], uf = au[m][n][j];
          float hv = gf / (1.f + expf(-gf)) * uf;
          h[(size_t)(d.row_start + r) * F_DIM + col] = f2bf(hv);
        }
      }
    }
  }
}

// ======== GEMM2 (R7/R15-proven shape): eout(bf16)/out(f32) = H @ Wd, 128x256 ========
__global__ __launch_bounds__(256, 2) void k_gemm2(
    const u16* __restrict__ h, const u16* __restrict__ WdT, const u16* __restrict__ WdTs,
    const Desc* __restrict__ descs, u16* __restrict__ eout, float* __restrict__ out) {
  __shared__ u16 As[BM * BK];          // 16 KB
  __shared__ u16 Bs[256 * BK];         // 32 KB
  const Desc d = descs[blockIdx.y];
  if (d.nrows <= 0) return;
  const int n0 = (int)blockIdx.x * 256;
  const u16* BT = (d.e == NEXP) ? WdTs : (WdT + (size_t)d.e * D_DIM * F_DIM);
  const int tid = threadIdx.x;
  const int w = tid >> 6, lane = tid & 63;

  const u16* pA[4]; const u16* pB[8]; unsigned aoff[4], boff[8];
  const int lrow = lane >> 3;
  const int col = (((lane & 7) ^ (lrow & 7)) * 8);
  #pragma unroll
  for (int j = 0; j < 4; j++) {
    const int chunk = w * 4 + j;
    pA[j] = h + (size_t)(d.row_start + chunk * 8 + lrow) * F_DIM + col;
    aoff[j] = (unsigned)chunk * 1024u;
  }
  #pragma unroll
  for (int j = 0; j < 8; j++) {
    const int chunk = w * 8 + j;
    pB[j] = BT + (size_t)(n0 + chunk * 8 + lrow) * F_DIM + col;
    boff[j] = (unsigned)chunk * 1024u;
  }

  f32x4 acc[4][8];
  #pragma unroll
  for (int m = 0; m < 4; m++)
    #pragma unroll
    for (int n = 0; n < 8; n++) acc[m][n] = (f32x4)0.f;

  const int wr = w >> 1, wc = w & 1;
  const int sw = lane & 7;
  const u16* aP = As + (wr * 64 + (lane & 15)) * BK;
  const u16* bP = Bs + (wc * 128 + (lane & 15)) * BK;
  const int slot0 = ((lane >> 4) ^ sw) * 8;
  const int slot1 = (((lane >> 4) + 4) ^ sw) * 8;

  for (int k0 = 0; k0 < F_DIM; k0 += BK) {
    #pragma unroll
    for (int j = 0; j < 4; j++) GLD16(pA[j] + k0, (char*)As + aoff[j]);
    #pragma unroll
    for (int j = 0; j < 8; j++) GLD16(pB[j] + k0, (char*)Bs + boff[j]);
    __syncthreads();
    #pragma unroll
    for (int ks = 0; ks < 2; ks++) {
      const int sl = ks ? slot1 : slot0;
      bf16x8 af[4], bf[8];
      #pragma unroll
      for (int m = 0; m < 4; m++) af[m] = *(const bf16x8*)(aP + m * 16 * BK + sl);
      #pragma unroll
      for (int n = 0; n < 8; n++) bf[n] = *(const bf16x8*)(bP + n * 16 * BK + sl);
      #pragma unroll
      for (int m = 0; m < 4; m++)
        #pragma unroll
        for (int n = 0; n < 8; n++)
          acc[m][n] = __builtin_amdgcn_mfma_f32_16x16x32_bf16(af[m], bf[n], acc[m][n], 0, 0, 0);
    }
    __syncthreads();
  }

  #pragma unroll
  for (int m = 0; m < 4; m++) {
    const int rbase = wr * 64 + m * 16 + ((lane >> 4) << 2);
    #pragma unroll
    for (int n = 0; n < 8; n++) {
      const int col2 = n0 + wc * 128 + n * 16 + (lane & 15);
      #pragma unroll
      for (int j = 0; j < 4; j++) {
        const int r = rbase + j;
        if (r < d.nrows) {
          const int grow = d.row_start + r;
          float v = acc[m][n][j];
          if (d.e == NEXP) out[(size_t)(grow - 2 * T_TOK) * D_DIM + col2] = v;
          else             eout[(size_t)grow * D_DIM + col2] = f2bf(v);
        }
      }
    }
  }
}

// ------- combine (grid-strided, 1024 blocks x 4 rows): out[t] += w0*e[p0]+w1*e[p1] -------
__global__ void k_combine(const u16* __restrict__ eout, const int* __restrict__ pos,
                          const float* __restrict__ tk_w, float* __restrict__ out) {
  const int t = blockIdx.x * 4 + (threadIdx.x >> 6);
  const int dc = (threadIdx.x & 63) * 4;
  const int p0 = pos[t * 2], p1 = pos[t * 2 + 1];
  const float w0 = tk_w[t * 2], w1 = tk_w[t * 2 + 1];
  #pragma unroll
  for (int h = 0; h < 4; h++) {
    const int c = dc + (h & 1) * 256 + (h >> 1) * 512;
    float* op = out + (size_t)t * D_DIM + c;
    float4 o = *(float4*)op;
    union { uint2 v; u16 a[4]; } av, bv;
    av.v = *(const uint2*)(eout + (size_t)p0 * D_DIM + c);
    bv.v = *(const uint2*)(eout + (size_t)p1 * D_DIM + c);
    o.x += w0 * bf2f(av.a[0]) + w1 * bf2f(bv.a[0]);
    o.y += w0 * bf2f(av.a[1]) + w1 * bf2f(bv.a[1]);
    o.z += w0 * bf2f(av.a[2]) + w1 * bf2f(bv.a[2]);
    o.w += w0 * bf2f(av.a[3]) + w1 * bf2f(bv.a[3]);
    *(float4*)op = o;
  }
}

extern "C" void kernel_launch(void* const* d_in, const int* in_sizes, int n_in,
                              void* d_out, int out_size, void* d_ws, size_t ws_size,
                              hipStream_t stream) {
  const float* X    = (const float*)d_in[0];
  const float* Wr   = (const float*)d_in[1];
  const float* Wg_s = (const float*)d_in[2];
  const float* Wu_s = (const float*)d_in[3];
  const float* Wd_s = (const float*)d_in[4];
  const float* Wg   = (const float*)d_in[5];
  const float* Wu   = (const float*)d_in[6];
  const float* Wd   = (const float*)d_in[7];
  float* out = (float*)d_out;

  char* ws = (char*)d_ws;
  size_t o = 0;
  auto alloc = [&](size_t bytes) -> void* {
    void* p = ws + o;
    o += (bytes + 255) & ~(size_t)255;
    return p;
  };
  u16* Xb    = (u16*)alloc((size_t)T_TOK * D_DIM * 2);
  u16* WgTs  = (u16*)alloc((size_t)F_DIM * D_DIM * 2);
  u16* WuTs  = (u16*)alloc((size_t)F_DIM * D_DIM * 2);
  u16* WdTs  = (u16*)alloc((size_t)D_DIM * F_DIM * 2);
  u16* WgT   = (u16*)alloc((size_t)NEXP * F_DIM * D_DIM * 2);
  u16* WuT   = (u16*)alloc((size_t)NEXP * F_DIM * D_DIM * 2);
  u16* WdT   = (u16*)alloc((size_t)NEXP * D_DIM * F_DIM * 2);
  u16* h     = (u16*)alloc((size_t)(3 * T_TOK) * F_DIM * 2);
  u16* eout  = (u16*)alloc((size_t)(2 * T_TOK) * D_DIM * 2);
  int* tk_idx= (int*)alloc((size_t)T_TOK * 2 * 4);
  float* tk_w= (float*)alloc((size_t)T_TOK * 2 * 4);
  int* pos   = (int*)alloc((size_t)T_TOK * 2 * 4);
  int* tok   = (int*)alloc((size_t)(3 * T_TOK) * 4);
  Desc* descs= (Desc*)alloc(NDESC * sizeof(Desc));
  if (o > ws_size) return;

  k_prep<<<dim3(16, 32, 29), 256, 0, stream>>>(X, Wr, Wg_s, Wu_s, Wd_s, Wg, Wu, Wd,
                                               Xb, WgTs, WuTs, WdTs, WgT, WuT, WdT,
                                               tk_idx, tk_w);
  k_scan_scatter<<<1, 1024, 0, stream>>>(tk_idx, descs, tok, pos);
  k_gemm1<<<dim3(32, NDESC), 256, 0, stream>>>(Xb, WgT, WuT, WgTs, WuTs, tok, descs, h);
  k_gemm2<<<dim3(4, NDESC), 256, 0, stream>>>(h, WdT, WdTs, descs, eout, out);
  k_combine<<<T_TOK / 4, 256, 0, stream>>>(eout, pos, tk_w, out);
}